// Round 8
// baseline (141.741 us; speedup 1.0000x reference)
//
#include <hip/hip_runtime.h>
#include <hip/hip_bf16.h>
#include <cstdint>

#define DIM   1024
#define HEADS 16
#define BB    32
#define NN    2048
#define DH    64
#define TCAP  32   // max 64-slot tiles per batch (count <= 2048)

constexpr float SCALE = 0.03125f;  // 1/sqrt(1024)
constexpr float LN_EPS = 1e-5f;

typedef __attribute__((ext_vector_type(8))) short short8v;
typedef __attribute__((ext_vector_type(4))) short short4v;
typedef __attribute__((ext_vector_type(4))) float f32x4;

__device__ __forceinline__ short f2bf(float f) {
  union { __hip_bfloat16 h; short s; } u;
  u.h = __float2bfloat16(f);
  return u.s;
}
__device__ __forceinline__ float bf2f(short s) {
  union { unsigned int i; float f; } u;
  u.i = ((unsigned int)(unsigned short)s) << 16;
  return u.f;
}
__device__ __forceinline__ short8v pack8(float4 a, float4 b) {
  short8v v;
  v[0] = f2bf(a.x); v[1] = f2bf(a.y); v[2] = f2bf(a.z); v[3] = f2bf(a.w);
  v[4] = f2bf(b.x); v[5] = f2bf(b.y); v[6] = f2bf(b.z); v[7] = f2bf(b.w);
  return v;
}
__device__ __forceinline__ void fma4(float4& a, float s, float4 x) {
  a.x += s * x.x; a.y += s * x.y; a.z += s * x.z; a.w += s * x.w;
}

__device__ __forceinline__ float block_sum256(float v, volatile float* red) {
  #pragma unroll
  for (int off = 32; off; off >>= 1) v += __shfl_xor(v, off);
  __syncthreads();
  if ((threadIdx.x & 63) == 0) red[threadIdx.x >> 6] = v;
  __syncthreads();
  return red[0] + red[1] + red[2] + red[3];
}

// ---------------- K0: blocks 0-63 = qk projection (bf16 swizzled); 64-95 = index compaction ----------------
__global__ void k_front(const int* __restrict__ mask, const float* __restrict__ S,
                        const float* __restrict__ Wq, const float* __restrict__ bq,
                        const float* __restrict__ Wk, const float* __restrict__ bk,
                        short* __restrict__ qk_bf, float* __restrict__ qb,
                        int* __restrict__ idx, int* __restrict__ cnt) {
  __shared__ float qpl[DH];
  __shared__ int wsum[4];
  int tid = threadIdx.x;
  if (blockIdx.x >= 64) {
    int b = blockIdx.x - 64;
    const int* mb = mask + b * NN;
    int base = tid * 8;
    int loc[8], c = 0;
    #pragma unroll
    for (int i = 0; i < 8; ++i) { loc[i] = mb[base + i]; c += (loc[i] != 0); }
    int pre = c;
    #pragma unroll
    for (int off = 1; off < 64; off <<= 1) {
      int y = __shfl_up(pre, off);
      if ((tid & 63) >= off) pre += y;
    }
    if ((tid & 63) == 63) wsum[tid >> 6] = pre;
    __syncthreads();
    int wo = 0;
    for (int wv = 0; wv < (tid >> 6); ++wv) wo += wsum[wv];
    int pos = wo + pre - c;
    int* ib = idx + b * NN;
    #pragma unroll
    for (int i = 0; i < 8; ++i) if (loc[i]) ib[pos++] = base + i;
    if (tid == 255) cnt[b] = wo + pre;
    return;
  }
  int h = blockIdx.x >> 2, cblk = blockIdx.x & 3;
  int r = tid >> 2, j = tid & 3;               // 4 threads per Wq row
  int d = h * DH + r;
  const float* wr = Wq + (size_t)d * DIM + j * 256;
  const float* sp = S + j * 256;
  float a = 0.f;
  #pragma unroll 8
  for (int k = 0; k < 64; ++k) {
    float4 av = *(const float4*)(wr + k * 4);
    float4 sv = *(const float4*)(sp + k * 4);
    a += av.x * sv.x + av.y * sv.y + av.z * sv.z + av.w * sv.w;
  }
  a += __shfl_xor(a, 1);
  a += __shfl_xor(a, 2);
  if (j == 0) qpl[r] = a + bq[d];
  __syncthreads();
  if (cblk == 0 && tid < 64) {                 // qb[h] = Qp[h,:] . bk[h,:]
    float v = qpl[tid] * bk[h * DH + tid];
    #pragma unroll
    for (int off = 32; off; off >>= 1) v += __shfl_xor(v, off);
    if (tid == 0) qb[h] = v;
  }
  int c = cblk * 256 + tid;
  float acc = 0.f;
  #pragma unroll 8
  for (int d0 = 0; d0 < DH; ++d0)
    acc += qpl[d0] * Wk[(size_t)(h * DH + d0) * DIM + c];
  int slot = (c >> 3) ^ (h & 7);               // pre-swizzled bf16 layout
  qk_bf[h * 1024 + slot * 8 + (c & 7)] = f2bf(acc);
}

// ---------------- K1: fused scores + tile-softmax + weighted X accumulation ----------------
// grid 512 = 32 b x 16 tg; per 64-slot tile: MFMA QK^T, e=exp(s-m_t), Zt = sum e*X (X re-read L2-hot)
__global__ __launch_bounds__(256) void k_fused(const float* __restrict__ X,
                                               const short* __restrict__ qk_bf,
                                               const float* __restrict__ qb,
                                               const int* __restrict__ idx,
                                               const int* __restrict__ cnt,
                                               short* __restrict__ Zt,
                                               float* __restrict__ mt_g,
                                               float* __restrict__ lt_g) {
  int b  = blockIdx.x >> 4;
  int tg = blockIdx.x & 15;
  int count = cnt[b];
  int ntiles = (count + 63) >> 6;
  if (tg >= ntiles) return;
  __shared__ short qlds[HEADS * 1024];         // 32 KB bf16, pre-swizzled
  __shared__ float el[64 * HEADS];             // 4 KB: e[slot][h]
  __shared__ float mt_l[4 * HEADS];            // per-wave max
  __shared__ float lt_l[4 * HEADS];            // per-wave sum
  int tid = threadIdx.x;
  {
    const short8v* qg = (const short8v*)qk_bf;
    short8v* ql = (short8v*)qlds;
    #pragma unroll
    for (int i = 0; i < 8; ++i) ql[tid + i * 256] = qg[tid + i * 256];
  }
  __syncthreads();
  int wv = tid >> 6, lane = tid & 63;
  int r16 = lane & 15, kg = lane >> 4;
  const short* qrow = qlds + r16 * 1024;
  int hx = r16 & 7;
  const int* ib = idx + b * NN;
  float qbv = qb[r16];
  const float* Xb = X + (size_t)b * NN * DIM;
  const float* Xc = Xb + tid * 4;              // phase-C column base

  for (int t = tg; t < ntiles; t += 16) {
    // ---- phase A: QK^T for this wave's 16 slots ----
    int tilebase = t * 64 + wv * 16;
    int s0 = tilebase + r16;
    int c0 = s0 < count ? s0 : count - 1;
    int i0 = ib[c0];
    const float* x0 = Xb + (size_t)i0 * DIM + kg * 8;
    f32x4 accA = {0.f, 0.f, 0.f, 0.f}, accB = {0.f, 0.f, 0.f, 0.f};
    #pragma unroll 4
    for (int k0 = 0; k0 < DIM; k0 += 64) {
      float4 a00 = *(const float4*)(x0 + k0);
      float4 a01 = *(const float4*)(x0 + k0 + 4);
      float4 a10 = *(const float4*)(x0 + k0 + 32);
      float4 a11 = *(const float4*)(x0 + k0 + 36);
      short8v b0 = *(const short8v*)(qrow + ((((k0 >> 3) + kg) ^ hx) << 3));
      short8v b1 = *(const short8v*)(qrow + ((((k0 >> 3) + 4 + kg) ^ hx) << 3));
      accA = __builtin_amdgcn_mfma_f32_16x16x32_bf16(pack8(a00, a01), b0, accA, 0, 0, 0);
      accB = __builtin_amdgcn_mfma_f32_16x16x32_bf16(pack8(a10, a11), b1, accB, 0, 0, 0);
    }
    f32x4 acc = accA + accB;
    // lane holds scores s[slot = tilebase+kg*4+j][head = r16]
    float s_[4];
    #pragma unroll
    for (int j = 0; j < 4; ++j) {
      int os = tilebase + kg * 4 + j;
      s_[j] = (os < count) ? (acc[j] + qbv) * SCALE : -3e38f;
    }
    float mw = fmaxf(fmaxf(s_[0], s_[1]), fmaxf(s_[2], s_[3]));
    mw = fmaxf(mw, __shfl_xor(mw, 16));
    mw = fmaxf(mw, __shfl_xor(mw, 32));
    __syncthreads();                           // A: prev iter's el/mt_l/lt_l consumers done
    if (kg == 0) mt_l[wv * 16 + r16] = mw;
    __syncthreads();                           // B: mt_l ready
    float m_t = fmaxf(fmaxf(mt_l[r16], mt_l[16 + r16]),
                      fmaxf(mt_l[32 + r16], mt_l[48 + r16]));
    float es = 0.f;
    #pragma unroll
    for (int j = 0; j < 4; ++j) {
      float e = (s_[j] > -1e30f) ? __expf(s_[j] - m_t) : 0.f;
      el[(wv * 16 + kg * 4 + j) * HEADS + r16] = e;
      es += e;
    }
    es += __shfl_xor(es, 16);
    es += __shfl_xor(es, 32);
    if (kg == 0) lt_l[wv * 16 + r16] = es;
    __syncthreads();                           // C: el, lt_l ready
    if (tid < 16) {
      float mm = fmaxf(fmaxf(mt_l[tid], mt_l[16 + tid]),
                       fmaxf(mt_l[32 + tid], mt_l[48 + tid]));
      float ll = lt_l[tid] + lt_l[16 + tid] + lt_l[32 + tid] + lt_l[48 + tid];
      mt_g[(b * TCAP + t) * HEADS + tid] = mm;
      lt_g[(b * TCAP + t) * HEADS + tid] = ll;
    }
    // ---- phase C: Zt[h][c] = sum_slot e[slot][h] * X[slot][c]  (X from L2) ----
    int smax = count - t * 64; if (smax > 64) smax = 64;
    float4 z[HEADS];
    #pragma unroll
    for (int h = 0; h < HEADS; ++h) z[h] = make_float4(0.f, 0.f, 0.f, 0.f);
    const int* ibt = ib + t * 64;
    #pragma unroll 2
    for (int slot = 0; slot < smax; ++slot) {
      int n = ibt[slot];
      float4 x4 = *(const float4*)(Xc + (size_t)n * DIM);
      const float4* ep = (const float4*)(el + slot * HEADS);
      float4 e0 = ep[0], e1 = ep[1], e2 = ep[2], e3 = ep[3];  // broadcast reads
      fma4(z[0],  e0.x, x4); fma4(z[1],  e0.y, x4);
      fma4(z[2],  e0.z, x4); fma4(z[3],  e0.w, x4);
      fma4(z[4],  e1.x, x4); fma4(z[5],  e1.y, x4);
      fma4(z[6],  e1.z, x4); fma4(z[7],  e1.w, x4);
      fma4(z[8],  e2.x, x4); fma4(z[9],  e2.y, x4);
      fma4(z[10], e2.z, x4); fma4(z[11], e2.w, x4);
      fma4(z[12], e3.x, x4); fma4(z[13], e3.y, x4);
      fma4(z[14], e3.z, x4); fma4(z[15], e3.w, x4);
    }
    short* zrow = Zt + ((size_t)(b * TCAP + t) * HEADS) * DIM + tid * 4;
    #pragma unroll
    for (int h = 0; h < HEADS; ++h) {
      short4v z4;
      z4[0] = f2bf(z[h].x); z4[1] = f2bf(z[h].y);
      z4[2] = f2bf(z[h].z); z4[3] = f2bf(z[h].w);
      *(short4v*)(zrow + (size_t)h * DIM) = z4;
    }
  }
}

// ---------------- K2: reduce tiles (flash rescale) + Wv projection ----------------
__global__ __launch_bounds__(256) void k_tov(const short* __restrict__ Zt,
                                             const float* __restrict__ mt_g,
                                             const float* __restrict__ lt_g,
                                             const int* __restrict__ cnt,
                                             const float* __restrict__ Wv,
                                             float* __restrict__ T,
                                             float* __restrict__ lsum) {
  int b = blockIdx.x >> 4, h = blockIdx.x & 15;   // grid 512
  int tid = threadIdx.x;
  int count = cnt[b];
  int ntiles = (count + 63) >> 6;
  __shared__ float zlds[DIM];
  float m_b = -3e38f;
  for (int t = 0; t < ntiles; ++t)
    m_b = fmaxf(m_b, mt_g[(b * TCAP + t) * HEADS + h]);
  float L = 0.f;
  for (int t = 0; t < ntiles; ++t)
    L += lt_g[(b * TCAP + t) * HEADS + h] * __expf(mt_g[(b * TCAP + t) * HEADS + h] - m_b);
  float inv = L > 0.f ? 1.f / L : 0.f;
  float4 zs = make_float4(0.f, 0.f, 0.f, 0.f);
  for (int t = 0; t < ntiles; ++t) {
    float f = __expf(mt_g[(b * TCAP + t) * HEADS + h] - m_b) * inv;
    short4v z4 = *(const short4v*)(Zt + ((size_t)(b * TCAP + t) * HEADS + h) * DIM + tid * 4);
    zs.x += f * bf2f(z4[0]); zs.y += f * bf2f(z4[1]);
    zs.z += f * bf2f(z4[2]); zs.w += f * bf2f(z4[3]);
  }
  *(float4*)(zlds + tid * 4) = zs;
  __syncthreads();
  int wv = tid >> 6, lane = tid & 63;
  float4 zr[4];
  #pragma unroll
  for (int j = 0; j < 4; ++j) zr[j] = *(const float4*)(zlds + lane * 4 + j * 256);
  for (int i = 0; i < 16; ++i) {
    int df = h * 64 + wv * 16 + i;
    const float* wr = Wv + (size_t)df * DIM + lane * 4;
    float a = 0.f;
    #pragma unroll
    for (int j = 0; j < 4; ++j) {
      float4 w4 = *(const float4*)(wr + j * 256);
      a += zr[j].x * w4.x + zr[j].y * w4.y + zr[j].z * w4.z + zr[j].w * w4.w;
    }
    #pragma unroll
    for (int off = 32; off; off >>= 1) a += __shfl_xor(a, off);
    if (lane == 0) T[(size_t)b * DIM + df] = a;
  }
  if (tid == 0) lsum[b * HEADS + h] = L > 0.f ? 1.f : 0.f;
}

// ---------------- K3: U = LN0(S + T + l*bv) ----------------
__global__ void k_ln0(const float* __restrict__ S, const float* __restrict__ T,
                      const float* __restrict__ lsum, const float* __restrict__ bv,
                      const float* __restrict__ g0, const float* __restrict__ b0,
                      float* __restrict__ U) {
  __shared__ float red[4];
  int b = blockIdx.x, tid = threadIdx.x, d0 = tid * 4;   // grid 32
  float4 s4 = *(const float4*)(S + d0);
  float4 t4 = *(const float4*)(T + (size_t)b * DIM + d0);
  float4 v4 = *(const float4*)(bv + d0);
  float lh = lsum[b * HEADS + (d0 >> 6)];
  float x0 = s4.x + t4.x + lh * v4.x;
  float x1 = s4.y + t4.y + lh * v4.y;
  float x2 = s4.z + t4.z + lh * v4.z;
  float x3 = s4.w + t4.w + lh * v4.w;
  float mu = block_sum256(x0 + x1 + x2 + x3, red) * (1.f / DIM);
  float e0 = x0 - mu, e1 = x1 - mu, e2 = x2 - mu, e3 = x3 - mu;
  float var = block_sum256(e0 * e0 + e1 * e1 + e2 * e2 + e3 * e3, red) * (1.f / DIM);
  float r = rsqrtf(var + LN_EPS);
  float4 g4 = *(const float4*)(g0 + d0);
  float4 bb4 = *(const float4*)(b0 + d0);
  float4 o;
  o.x = e0 * r * g4.x + bb4.x;
  o.y = e1 * r * g4.y + bb4.y;
  o.z = e2 * r * g4.z + bb4.z;
  o.w = e3 * r * g4.w + bb4.w;
  *(float4*)(U + (size_t)b * DIM + d0) = o;
}

// ---------------- K4: R = relu(U . Wo^T + bo) ----------------
__global__ void k_wo(const float* __restrict__ U, const float* __restrict__ Wo,
                     const float* __restrict__ bo, float* __restrict__ R) {
  int wave = threadIdx.x >> 6, lane = threadIdx.x & 63;
  int dfb = blockIdx.x;                       // grid 256
  for (int dot = wave; dot < 128; dot += 4) {
    int b = dot >> 2, dfl = dot & 3;
    int df = dfb * 4 + dfl;
    const float* wr = Wo + (size_t)df * DIM + lane * 4;
    const float* ur = U + (size_t)b * DIM + lane * 4;
    float acc = 0.f;
    #pragma unroll
    for (int k = 0; k < 4; ++k) {
      float4 a = *(const float4*)(wr + k * 256);
      float4 u = *(const float4*)(ur + k * 256);
      acc += a.x * u.x + a.y * u.y + a.z * u.z + a.w * u.w;
    }
    #pragma unroll
    for (int off = 32; off; off >>= 1) acc += __shfl_xor(acc, off);
    if (lane == 0) R[(size_t)b * DIM + df] = fmaxf(acc + bo[df], 0.f);
  }
}

// ---------------- K5: out = LN1(U + R) ----------------
__global__ void k_ln1(const float* __restrict__ U, const float* __restrict__ R,
                      const float* __restrict__ g1, const float* __restrict__ b1,
                      float* __restrict__ out) {
  __shared__ float red[4];
  int b = blockIdx.x, tid = threadIdx.x, d0 = tid * 4;   // grid 32
  float4 u4 = *(const float4*)(U + (size_t)b * DIM + d0);
  float4 r4 = *(const float4*)(R + (size_t)b * DIM + d0);
  float x0 = u4.x + r4.x, x1 = u4.y + r4.y, x2 = u4.z + r4.z, x3 = u4.w + r4.w;
  float mu = block_sum256(x0 + x1 + x2 + x3, red) * (1.f / DIM);
  float e0 = x0 - mu, e1 = x1 - mu, e2 = x2 - mu, e3 = x3 - mu;
  float var = block_sum256(e0 * e0 + e1 * e1 + e2 * e2 + e3 * e3, red) * (1.f / DIM);
  float r = rsqrtf(var + LN_EPS);
  float4 g4 = *(const float4*)(g1 + d0);
  float4 bb4 = *(const float4*)(b1 + d0);
  float4 o;
  o.x = e0 * r * g4.x + bb4.x;
  o.y = e1 * r * g4.y + bb4.y;
  o.z = e2 * r * g4.z + bb4.z;
  o.w = e3 * r * g4.w + bb4.w;
  *(float4*)(out + (size_t)b * DIM + d0) = o;
}

extern "C" void kernel_launch(void* const* d_in, const int* in_sizes, int n_in,
                              void* d_out, int out_size, void* d_ws, size_t ws_size,
                              hipStream_t stream) {
  (void)in_sizes; (void)n_in; (void)out_size; (void)ws_size;
  const float* X  = (const float*)d_in[0];
  const int*   mask = (const int*)d_in[1];
  const float* S  = (const float*)d_in[2];
  const float* Wq = (const float*)d_in[3];
  const float* bq = (const float*)d_in[4];
  const float* Wk = (const float*)d_in[5];
  const float* bk = (const float*)d_in[6];
  const float* Wv = (const float*)d_in[7];
  const float* bv = (const float*)d_in[8];
  const float* Wo = (const float*)d_in[9];
  const float* bo = (const float*)d_in[10];
  const float* g0 = (const float*)d_in[11];
  const float* b0 = (const float*)d_in[12];
  const float* g1 = (const float*)d_in[13];
  const float* b1 = (const float*)d_in[14];
  float* out = (float*)d_out;

  // workspace layout (ws_size ~1 GB per harness poison fill; we use ~34.5 MB)
  char* base  = (char*)d_ws;
  size_t off = 0;
  short* Zt   = (short*)(base + off); off += (size_t)BB * TCAP * HEADS * DIM * 2;  // 33.5 MB
  short* qkbf = (short*)(base + off); off += HEADS * 1024 * 2;                     // 32 KB
  float* qb   = (float*)(base + off); off += 64;
  float* mt   = (float*)(base + off); off += (size_t)BB * TCAP * HEADS * 4;        // 64 KB
  float* lt   = (float*)(base + off); off += (size_t)BB * TCAP * HEADS * 4;        // 64 KB
  float* lsum = (float*)(base + off); off += BB * HEADS * 4;
  int*   idx  = (int*)(base + off);   off += (size_t)BB * NN * 4;                  // 256 KB
  int*   cnt  = (int*)(base + off);   off += 256;
  float* T    = (float*)(base + off); off += (size_t)BB * DIM * 4;
  float* U    = (float*)(base + off); off += (size_t)BB * DIM * 4;
  float* R    = (float*)(base + off); off += (size_t)BB * DIM * 4;

  k_front <<<96,  256, 0, stream>>>(mask, S, Wq, bq, Wk, bk, qkbf, qb, idx, cnt);
  k_fused <<<512, 256, 0, stream>>>(X, qkbf, qb, idx, cnt, Zt, mt, lt);
  k_tov   <<<512, 256, 0, stream>>>(Zt, mt, lt, cnt, Wv, T, lsum);
  k_ln0   <<<32,  256, 0, stream>>>(S, T, lsum, bv, g0, b0, U);
  k_wo    <<<256, 256, 0, stream>>>(U, Wo, bo, R);
  k_ln1   <<<32,  256, 0, stream>>>(U, R, g1, b1, out);
}

// Round 9
// 110.024 us; speedup vs baseline: 1.2883x; 1.2883x over previous
//
#include <hip/hip_runtime.h>
#include <hip/hip_bf16.h>
#include <cstdint>

#define DIM   1024
#define HEADS 16
#define BB    32
#define NN    2048
#define DH    64
#define PARTS 8    // per-batch partitions (one block each)
#define TS    32   // slots per LDS tile

constexpr float SCALE = 0.03125f;  // 1/sqrt(1024)
constexpr float LN_EPS = 1e-5f;

typedef __attribute__((ext_vector_type(8))) short short8v;
typedef __attribute__((ext_vector_type(4))) short short4v;
typedef __attribute__((ext_vector_type(4))) float f32x4;

__device__ __forceinline__ short f2bf(float f) {
  union { __hip_bfloat16 h; short s; } u;
  u.h = __float2bfloat16(f);
  return u.s;
}
__device__ __forceinline__ float bf2f(short s) {
  union { unsigned int i; float f; } u;
  u.i = ((unsigned int)(unsigned short)s) << 16;
  return u.f;
}
__device__ __forceinline__ short8v pack8(float4 a, float4 b) {
  short8v v;
  v[0] = f2bf(a.x); v[1] = f2bf(a.y); v[2] = f2bf(a.z); v[3] = f2bf(a.w);
  v[4] = f2bf(b.x); v[5] = f2bf(b.y); v[6] = f2bf(b.z); v[7] = f2bf(b.w);
  return v;
}

__device__ __forceinline__ float block_sum256(float v, volatile float* red) {
  #pragma unroll
  for (int off = 32; off; off >>= 1) v += __shfl_xor(v, off);
  __syncthreads();
  if ((threadIdx.x & 63) == 0) red[threadIdx.x >> 6] = v;
  __syncthreads();
  return red[0] + red[1] + red[2] + red[3];
}

// ---------------- K0: blocks 0-63 = qk projection (bf16 swizzled); 64-95 = index compaction ----------------
__global__ void k_front(const int* __restrict__ mask, const float* __restrict__ S,
                        const float* __restrict__ Wq, const float* __restrict__ bq,
                        const float* __restrict__ Wk, const float* __restrict__ bk,
                        short* __restrict__ qk_bf, float* __restrict__ qb,
                        int* __restrict__ idx, int* __restrict__ cnt) {
  __shared__ float qpl[DH];
  __shared__ int wsum[4];
  int tid = threadIdx.x;
  if (blockIdx.x >= 64) {
    int b = blockIdx.x - 64;
    const int* mb = mask + b * NN;
    int base = tid * 8;
    int loc[8], c = 0;
    #pragma unroll
    for (int i = 0; i < 8; ++i) { loc[i] = mb[base + i]; c += (loc[i] != 0); }
    int pre = c;
    #pragma unroll
    for (int off = 1; off < 64; off <<= 1) {
      int y = __shfl_up(pre, off);
      if ((tid & 63) >= off) pre += y;
    }
    if ((tid & 63) == 63) wsum[tid >> 6] = pre;
    __syncthreads();
    int wo = 0;
    for (int wv = 0; wv < (tid >> 6); ++wv) wo += wsum[wv];
    int pos = wo + pre - c;
    int* ib = idx + b * NN;
    #pragma unroll
    for (int i = 0; i < 8; ++i) if (loc[i]) ib[pos++] = base + i;
    if (tid == 255) cnt[b] = wo + pre;
    return;
  }
  int h = blockIdx.x >> 2, cblk = blockIdx.x & 3;
  int r = tid >> 2, j = tid & 3;               // 4 threads per Wq row
  int d = h * DH + r;
  const float* wr = Wq + (size_t)d * DIM + j * 256;
  const float* sp = S + j * 256;
  float a = 0.f;
  #pragma unroll 8
  for (int k = 0; k < 64; ++k) {
    float4 av = *(const float4*)(wr + k * 4);
    float4 sv = *(const float4*)(sp + k * 4);
    a += av.x * sv.x + av.y * sv.y + av.z * sv.z + av.w * sv.w;
  }
  a += __shfl_xor(a, 1);
  a += __shfl_xor(a, 2);
  if (j == 0) qpl[r] = a + bq[d];
  __syncthreads();
  if (cblk == 0 && tid < 64) {                 // qb[h] = Qp[h,:] . bk[h,:]
    float v = qpl[tid] * bk[h * DH + tid];
    #pragma unroll
    for (int off = 32; off; off >>= 1) v += __shfl_xor(v, off);
    if (tid == 0) qb[h] = v;
  }
  int c = cblk * 256 + tid;
  float acc = 0.f;
  #pragma unroll 8
  for (int d0 = 0; d0 < DH; ++d0)
    acc += qpl[d0] * Wk[(size_t)(h * DH + d0) * DIM + c];
  int slot = (c >> 3) ^ (h & 7);               // pre-swizzled bf16 layout
  qk_bf[h * 1024 + slot * 8 + (c & 7)] = f2bf(acc);
}

// ---------------- K1: flash-fused attention. grid 256 = 32 b x 8 parts, 512 threads ----------------
// Per 32-slot tile: stage X->LDS bf16 once; QK^T from LDS (waves 0-1); online softmax;
// Z[h][2 cols] accumulated in registers with running (m,l) rescale. One Zt partial per block.
__global__ __launch_bounds__(512, 1) void k_fused2(const float* __restrict__ X,
                                                   const short* __restrict__ qk_bf,
                                                   const float* __restrict__ qb,
                                                   const int* __restrict__ idx,
                                                   const int* __restrict__ cnt,
                                                   short* __restrict__ Zt,
                                                   float* __restrict__ mt_g,
                                                   float* __restrict__ lt_g) {
  __shared__ short qlds[HEADS * 1024];   // 32 KB bf16, pre-swizzled
  __shared__ short xlds[TS * 1024];      // 64 KB bf16, XOR-swizzled rows
  __shared__ float el[TS * HEADS];       // 2 KB
  __shared__ float mt_l[32], lt_l[32], f_l[HEADS];
  __shared__ float mrun[2][HEADS], lrun[2][HEADS];
  int tid = threadIdx.x;
  int b = blockIdx.x >> 3, p = blockIdx.x & 7;
  int count = cnt[b];
  int chunk = (count + PARTS - 1) / PARTS;
  int pstart = p * chunk;
  int pend = pstart + chunk; if (pend > count) pend = count;
  int len = pend - pstart;
  int ntsub = (len + TS - 1) / TS;       // uniform per block
  {
    const short8v* qg = (const short8v*)qk_bf;
    short8v* ql = (short8v*)qlds;
    #pragma unroll
    for (int i = 0; i < 4; ++i) ql[tid + i * 512] = qg[tid + i * 512];
  }
  if (tid < HEADS) { mrun[0][tid] = -3e38f; lrun[0][tid] = 0.f; }
  float2 Z[HEADS];
  #pragma unroll
  for (int h = 0; h < HEADS; ++h) Z[h] = make_float2(0.f, 0.f);
  int wv = tid >> 6, lane = tid & 63;
  int r16 = lane & 15, kg = lane >> 4;
  int hx = r16 & 7;
  const int* ib = idx + b * NN;
  const float* Xb = X + (size_t)b * NN * DIM;
  const short* qrow = qlds + r16 * 1024;
  float qbv = qb[r16];
  __syncthreads();                       // qlds + mrun/lrun init visible

  for (int t = 0; t < ntsub; ++t) {
    int tb = pstart + t * TS;
    int smax = pend - tb; if (smax > TS) smax = TS;
    int tpar = t & 1;
    __syncthreads();                     // S0: prev iter's xlds/el/f_l readers done
    // ---- stage 32 rows of X -> xlds (bf16, swizzle col8 ^= row&7) ----
    #pragma unroll
    for (int k = 0; k < 8; ++k) {
      int i = tid + k * 512;
      int row = i >> 7, c8 = i & 127;
      int sl = tb + row; if (sl >= pend) sl = pend - 1;   // clamp (len>=1)
      int n = ib[sl];
      const float4* xg = (const float4*)(Xb + (size_t)n * DIM + c8 * 8);
      float4 fA = xg[0], fB = xg[1];
      *(short8v*)(xlds + row * 1024 + ((c8 ^ (row & 7)) << 3)) = pack8(fA, fB);
    }
    __syncthreads();                     // S1: xlds ready
    float s_[4]; int vld[4];
    if (wv < 2) {
      // ---- QK^T: A = xlds rows (16 per wave), B = qlds heads; K=1024 ----
      const short* arow = xlds + (wv * 16 + r16) * 1024;
      f32x4 acc = {0.f, 0.f, 0.f, 0.f};
      #pragma unroll 8
      for (int m = 0; m < 32; ++m) {
        int a8 = ((4 * m + kg) ^ hx) << 3;
        short8v af = *(const short8v*)(arow + a8);
        short8v bf = *(const short8v*)(qrow + a8);
        acc = __builtin_amdgcn_mfma_f32_16x16x32_bf16(af, bf, acc, 0, 0, 0);
      }
      float mw = -3e38f;
      #pragma unroll
      for (int j = 0; j < 4; ++j) {
        int slot = tb + wv * 16 + kg * 4 + j;
        vld[j] = slot < pend;
        s_[j] = vld[j] ? (acc[j] + qbv) * SCALE : -3e38f;
        mw = fmaxf(mw, s_[j]);
      }
      mw = fmaxf(mw, __shfl_xor(mw, 16));
      mw = fmaxf(mw, __shfl_xor(mw, 32));
      if (kg == 0) mt_l[wv * 16 + r16] = mw;
    }
    __syncthreads();                     // S2: mt_l ready
    if (wv < 2) {
      float m_t = fmaxf(mt_l[r16], mt_l[16 + r16]);
      float mo = mrun[tpar][r16];
      float mn = fmaxf(mo, m_t);
      float es = 0.f;
      #pragma unroll
      for (int j = 0; j < 4; ++j) {
        float e = vld[j] ? __expf(s_[j] - mn) : 0.f;
        el[(wv * 16 + kg * 4 + j) * HEADS + r16] = e;
        es += e;
      }
      es += __shfl_xor(es, 16);
      es += __shfl_xor(es, 32);
      if (kg == 0) lt_l[wv * 16 + r16] = es;
      if (tid < 16) {                    // wave0, kg==0 lanes
        f_l[tid] = __expf(mo - mn);
        mrun[tpar ^ 1][tid] = mn;
      }
    }
    __syncthreads();                     // S3: el, lt_l, f_l ready
    // ---- phase C: Z = Z*f + sum_slot e[slot][h] * x[slot][c]  (all from LDS) ----
    {
      const float4* fp = (const float4*)f_l;
      float4 ff0 = fp[0], ff1 = fp[1], ff2 = fp[2], ff3 = fp[3];
      float fa[16] = {ff0.x, ff0.y, ff0.z, ff0.w, ff1.x, ff1.y, ff1.z, ff1.w,
                      ff2.x, ff2.y, ff2.z, ff2.w, ff3.x, ff3.y, ff3.z, ff3.w};
      #pragma unroll
      for (int h = 0; h < HEADS; ++h) { Z[h].x *= fa[h]; Z[h].y *= fa[h]; }
      int c8 = tid >> 2, co = (tid & 3) * 2;     // cols tid*2, tid*2+1
      #pragma unroll 2
      for (int slot = 0; slot < smax; ++slot) {
        unsigned int xw = *(const unsigned int*)(xlds + slot * 1024 + ((c8 ^ (slot & 7)) << 3) + co);
        float x0 = bf2f((short)(xw & 0xffffu));
        float x1 = bf2f((short)(xw >> 16));
        const float4* ep = (const float4*)(el + slot * HEADS);
        float4 e0 = ep[0], e1 = ep[1], e2 = ep[2], e3 = ep[3];
        float ea[16] = {e0.x, e0.y, e0.z, e0.w, e1.x, e1.y, e1.z, e1.w,
                        e2.x, e2.y, e2.z, e2.w, e3.x, e3.y, e3.z, e3.w};
        #pragma unroll
        for (int h = 0; h < HEADS; ++h) { Z[h].x += ea[h] * x0; Z[h].y += ea[h] * x1; }
      }
      if (tid < 16) {
        float lt = lt_l[tid] + lt_l[16 + tid];
        lrun[tpar ^ 1][tid] = lrun[tpar][tid] * f_l[tid] + lt;
      }
    }
  }
  // ---- epilogue: write per-part partial ----
  int par = ntsub & 1;
  if (tid < 16) {
    mt_g[(b * PARTS + p) * HEADS + tid] = mrun[par][tid];
    lt_g[(b * PARTS + p) * HEADS + tid] = lrun[par][tid];
  }
  short* zrow = Zt + ((size_t)(b * PARTS + p) * HEADS) * DIM + tid * 2;
  #pragma unroll
  for (int h = 0; h < HEADS; ++h) {
    unsigned int w = (unsigned int)(unsigned short)f2bf(Z[h].x) |
                     ((unsigned int)(unsigned short)f2bf(Z[h].y) << 16);
    *(unsigned int*)(zrow + (size_t)h * DIM) = w;
  }
}

// ---------------- K2: reduce parts (flash rescale) + Wv projection ----------------
__global__ __launch_bounds__(256) void k_tov(const short* __restrict__ Zt,
                                             const float* __restrict__ mt_g,
                                             const float* __restrict__ lt_g,
                                             const float* __restrict__ Wv,
                                             float* __restrict__ T,
                                             float* __restrict__ lsum) {
  int b = blockIdx.x >> 4, h = blockIdx.x & 15;   // grid 512
  int tid = threadIdx.x;
  __shared__ float zlds[DIM];
  float m_b = -3e38f;
  #pragma unroll
  for (int t = 0; t < PARTS; ++t)
    m_b = fmaxf(m_b, mt_g[(b * PARTS + t) * HEADS + h]);
  float L = 0.f;
  #pragma unroll
  for (int t = 0; t < PARTS; ++t) {
    float lt = lt_g[(b * PARTS + t) * HEADS + h];
    if (lt > 0.f) L += lt * __expf(mt_g[(b * PARTS + t) * HEADS + h] - m_b);
  }
  float inv = L > 0.f ? 1.f / L : 0.f;
  float4 zs = make_float4(0.f, 0.f, 0.f, 0.f);
  #pragma unroll
  for (int t = 0; t < PARTS; ++t) {
    float lt = lt_g[(b * PARTS + t) * HEADS + h];
    if (lt <= 0.f) continue;
    float f = __expf(mt_g[(b * PARTS + t) * HEADS + h] - m_b) * inv;
    short4v z4 = *(const short4v*)(Zt + ((size_t)(b * PARTS + t) * HEADS + h) * DIM + tid * 4);
    zs.x += f * bf2f(z4[0]); zs.y += f * bf2f(z4[1]);
    zs.z += f * bf2f(z4[2]); zs.w += f * bf2f(z4[3]);
  }
  *(float4*)(zlds + tid * 4) = zs;
  __syncthreads();
  int wv = tid >> 6, lane = tid & 63;
  float4 zr[4];
  #pragma unroll
  for (int j = 0; j < 4; ++j) zr[j] = *(const float4*)(zlds + lane * 4 + j * 256);
  for (int i = 0; i < 16; ++i) {
    int df = h * 64 + wv * 16 + i;
    const float* wr = Wv + (size_t)df * DIM + lane * 4;
    float a = 0.f;
    #pragma unroll
    for (int j = 0; j < 4; ++j) {
      float4 w4 = *(const float4*)(wr + j * 256);
      a += zr[j].x * w4.x + zr[j].y * w4.y + zr[j].z * w4.z + zr[j].w * w4.w;
    }
    #pragma unroll
    for (int off = 32; off; off >>= 1) a += __shfl_xor(a, off);
    if (lane == 0) T[(size_t)b * DIM + df] = a;
  }
  if (tid == 0) lsum[b * HEADS + h] = L > 0.f ? 1.f : 0.f;
}

// ---------------- K3: U = LN0(S + T + l*bv) ----------------
__global__ void k_ln0(const float* __restrict__ S, const float* __restrict__ T,
                      const float* __restrict__ lsum, const float* __restrict__ bv,
                      const float* __restrict__ g0, const float* __restrict__ b0,
                      float* __restrict__ U) {
  __shared__ float red[4];
  int b = blockIdx.x, tid = threadIdx.x, d0 = tid * 4;   // grid 32
  float4 s4 = *(const float4*)(S + d0);
  float4 t4 = *(const float4*)(T + (size_t)b * DIM + d0);
  float4 v4 = *(const float4*)(bv + d0);
  float lh = lsum[b * HEADS + (d0 >> 6)];
  float x0 = s4.x + t4.x + lh * v4.x;
  float x1 = s4.y + t4.y + lh * v4.y;
  float x2 = s4.z + t4.z + lh * v4.z;
  float x3 = s4.w + t4.w + lh * v4.w;
  float mu = block_sum256(x0 + x1 + x2 + x3, red) * (1.f / DIM);
  float e0 = x0 - mu, e1 = x1 - mu, e2 = x2 - mu, e3 = x3 - mu;
  float var = block_sum256(e0 * e0 + e1 * e1 + e2 * e2 + e3 * e3, red) * (1.f / DIM);
  float r = rsqrtf(var + LN_EPS);
  float4 g4 = *(const float4*)(g0 + d0);
  float4 bb4 = *(const float4*)(b0 + d0);
  float4 o;
  o.x = e0 * r * g4.x + bb4.x;
  o.y = e1 * r * g4.y + bb4.y;
  o.z = e2 * r * g4.z + bb4.z;
  o.w = e3 * r * g4.w + bb4.w;
  *(float4*)(U + (size_t)b * DIM + d0) = o;
}

// ---------------- K4: R = relu(U . Wo^T + bo) ----------------
__global__ void k_wo(const float* __restrict__ U, const float* __restrict__ Wo,
                     const float* __restrict__ bo, float* __restrict__ R) {
  int wave = threadIdx.x >> 6, lane = threadIdx.x & 63;
  int dfb = blockIdx.x;                       // grid 256
  for (int dot = wave; dot < 128; dot += 4) {
    int b = dot >> 2, dfl = dot & 3;
    int df = dfb * 4 + dfl;
    const float* wr = Wo + (size_t)df * DIM + lane * 4;
    const float* ur = U + (size_t)b * DIM + lane * 4;
    float acc = 0.f;
    #pragma unroll
    for (int k = 0; k < 4; ++k) {
      float4 a = *(const float4*)(wr + k * 256);
      float4 u = *(const float4*)(ur + k * 256);
      acc += a.x * u.x + a.y * u.y + a.z * u.z + a.w * u.w;
    }
    #pragma unroll
    for (int off = 32; off; off >>= 1) acc += __shfl_xor(acc, off);
    if (lane == 0) R[(size_t)b * DIM + df] = fmaxf(acc + bo[df], 0.f);
  }
}

// ---------------- K5: out = LN1(U + R) ----------------
__global__ void k_ln1(const float* __restrict__ U, const float* __restrict__ R,
                      const float* __restrict__ g1, const float* __restrict__ b1,
                      float* __restrict__ out) {
  __shared__ float red[4];
  int b = blockIdx.x, tid = threadIdx.x, d0 = tid * 4;   // grid 32
  float4 u4 = *(const float4*)(U + (size_t)b * DIM + d0);
  float4 r4 = *(const float4*)(R + (size_t)b * DIM + d0);
  float x0 = u4.x + r4.x, x1 = u4.y + r4.y, x2 = u4.z + r4.z, x3 = u4.w + r4.w;
  float mu = block_sum256(x0 + x1 + x2 + x3, red) * (1.f / DIM);
  float e0 = x0 - mu, e1 = x1 - mu, e2 = x2 - mu, e3 = x3 - mu;
  float var = block_sum256(e0 * e0 + e1 * e1 + e2 * e2 + e3 * e3, red) * (1.f / DIM);
  float r = rsqrtf(var + LN_EPS);
  float4 g4 = *(const float4*)(g1 + d0);
  float4 bb4 = *(const float4*)(b1 + d0);
  float4 o;
  o.x = e0 * r * g4.x + bb4.x;
  o.y = e1 * r * g4.y + bb4.y;
  o.z = e2 * r * g4.z + bb4.z;
  o.w = e3 * r * g4.w + bb4.w;
  *(float4*)(out + (size_t)b * DIM + d0) = o;
}

extern "C" void kernel_launch(void* const* d_in, const int* in_sizes, int n_in,
                              void* d_out, int out_size, void* d_ws, size_t ws_size,
                              hipStream_t stream) {
  (void)in_sizes; (void)n_in; (void)out_size; (void)ws_size;
  const float* X  = (const float*)d_in[0];
  const int*   mask = (const int*)d_in[1];
  const float* S  = (const float*)d_in[2];
  const float* Wq = (const float*)d_in[3];
  const float* bq = (const float*)d_in[4];
  const float* Wk = (const float*)d_in[5];
  const float* bk = (const float*)d_in[6];
  const float* Wv = (const float*)d_in[7];
  const float* bv = (const float*)d_in[8];
  const float* Wo = (const float*)d_in[9];
  const float* bo = (const float*)d_in[10];
  const float* g0 = (const float*)d_in[11];
  const float* b0 = (const float*)d_in[12];
  const float* g1 = (const float*)d_in[13];
  const float* b1 = (const float*)d_in[14];
  float* out = (float*)d_out;

  char* base  = (char*)d_ws;
  size_t off = 0;
  short* Zt   = (short*)(base + off); off += (size_t)BB * PARTS * HEADS * DIM * 2;  // 8.4 MB
  short* qkbf = (short*)(base + off); off += HEADS * 1024 * 2;                      // 32 KB
  float* qb   = (float*)(base + off); off += 64;
  float* mt   = (float*)(base + off); off += (size_t)BB * PARTS * HEADS * 4;        // 16 KB
  float* lt   = (float*)(base + off); off += (size_t)BB * PARTS * HEADS * 4;        // 16 KB
  float* lsum = (float*)(base + off); off += BB * HEADS * 4;
  int*   idx  = (int*)(base + off);   off += (size_t)BB * NN * 4;                   // 256 KB
  int*   cnt  = (int*)(base + off);   off += 256;
  float* T    = (float*)(base + off); off += (size_t)BB * DIM * 4;
  float* U    = (float*)(base + off); off += (size_t)BB * DIM * 4;
  float* R    = (float*)(base + off); off += (size_t)BB * DIM * 4;

  k_front  <<<96,  256, 0, stream>>>(mask, S, Wq, bq, Wk, bk, qkbf, qb, idx, cnt);
  k_fused2 <<<256, 512, 0, stream>>>(X, qkbf, qb, idx, cnt, Zt, mt, lt);
  k_tov    <<<512, 256, 0, stream>>>(Zt, mt, lt, Wv, T, lsum);
  k_ln0    <<<32,  256, 0, stream>>>(S, T, lsum, bv, g0, b0, U);
  k_wo     <<<256, 256, 0, stream>>>(U, Wo, bo, R);
  k_ln1    <<<32,  256, 0, stream>>>(U, R, g1, b1, out);
}

// Round 10
// 93.855 us; speedup vs baseline: 1.5102x; 1.1723x over previous
//
#include <hip/hip_runtime.h>
#include <hip/hip_bf16.h>
#include <cstdint>

#define DIM   1024
#define HEADS 16
#define BB    32
#define NN    2048
#define DH    64
#define PARTS 8    // per-batch partitions (one block each)
#define TS    32   // slots per LDS tile

constexpr float SCALE = 0.03125f;  // 1/sqrt(1024)
constexpr float LN_EPS = 1e-5f;

typedef __attribute__((ext_vector_type(8))) short short8v;
typedef __attribute__((ext_vector_type(4))) short short4v;
typedef __attribute__((ext_vector_type(4))) float f32x4;

__device__ __forceinline__ short f2bf(float f) {
  union { __hip_bfloat16 h; short s; } u;
  u.h = __float2bfloat16(f);
  return u.s;
}
__device__ __forceinline__ float bf2f(short s) {
  union { unsigned int i; float f; } u;
  u.i = ((unsigned int)(unsigned short)s) << 16;
  return u.f;
}
__device__ __forceinline__ short8v pack8(float4 a, float4 b) {
  short8v v;
  v[0] = f2bf(a.x); v[1] = f2bf(a.y); v[2] = f2bf(a.z); v[3] = f2bf(a.w);
  v[4] = f2bf(b.x); v[5] = f2bf(b.y); v[6] = f2bf(b.z); v[7] = f2bf(b.w);
  return v;
}

__device__ __forceinline__ float block_sum256(float v, volatile float* red) {
  #pragma unroll
  for (int off = 32; off; off >>= 1) v += __shfl_xor(v, off);
  __syncthreads();
  if ((threadIdx.x & 63) == 0) red[threadIdx.x >> 6] = v;
  __syncthreads();
  return red[0] + red[1] + red[2] + red[3];
}

// ---------------- K0: blocks 0-63 = qk projection (bf16 swizzled); 64-95 = index compaction ----------------
__global__ void k_front(const int* __restrict__ mask, const float* __restrict__ S,
                        const float* __restrict__ Wq, const float* __restrict__ bq,
                        const float* __restrict__ Wk, const float* __restrict__ bk,
                        short* __restrict__ qk_bf, float* __restrict__ qb,
                        int* __restrict__ idx, int* __restrict__ cnt) {
  __shared__ float qpl[DH];
  __shared__ int wsum[4];
  int tid = threadIdx.x;
  if (blockIdx.x >= 64) {
    int b = blockIdx.x - 64;
    const int* mb = mask + b * NN;
    int base = tid * 8;
    int loc[8], c = 0;
    #pragma unroll
    for (int i = 0; i < 8; ++i) { loc[i] = mb[base + i]; c += (loc[i] != 0); }
    int pre = c;
    #pragma unroll
    for (int off = 1; off < 64; off <<= 1) {
      int y = __shfl_up(pre, off);
      if ((tid & 63) >= off) pre += y;
    }
    if ((tid & 63) == 63) wsum[tid >> 6] = pre;
    __syncthreads();
    int wo = 0;
    for (int wv = 0; wv < (tid >> 6); ++wv) wo += wsum[wv];
    int pos = wo + pre - c;
    int* ib = idx + b * NN;
    #pragma unroll
    for (int i = 0; i < 8; ++i) if (loc[i]) ib[pos++] = base + i;
    if (tid == 255) cnt[b] = wo + pre;
    return;
  }
  int h = blockIdx.x >> 2, cblk = blockIdx.x & 3;
  int r = tid >> 2, j = tid & 3;               // 4 threads per Wq row
  int d = h * DH + r;
  const float* wr = Wq + (size_t)d * DIM + j * 256;
  const float* sp = S + j * 256;
  float a = 0.f;
  #pragma unroll 8
  for (int k = 0; k < 64; ++k) {
    float4 av = *(const float4*)(wr + k * 4);
    float4 sv = *(const float4*)(sp + k * 4);
    a += av.x * sv.x + av.y * sv.y + av.z * sv.z + av.w * sv.w;
  }
  a += __shfl_xor(a, 1);
  a += __shfl_xor(a, 2);
  if (j == 0) qpl[r] = a + bq[d];
  __syncthreads();
  if (cblk == 0 && tid < 64) {                 // qb[h] = Qp[h,:] . bk[h,:]
    float v = qpl[tid] * bk[h * DH + tid];
    #pragma unroll
    for (int off = 32; off; off >>= 1) v += __shfl_xor(v, off);
    if (tid == 0) qb[h] = v;
  }
  int c = cblk * 256 + tid;
  float acc = 0.f;
  #pragma unroll 8
  for (int d0 = 0; d0 < DH; ++d0)
    acc += qpl[d0] * Wk[(size_t)(h * DH + d0) * DIM + c];
  int slot = (c >> 3) ^ (h & 7);               // pre-swizzled bf16 layout (qlds swizzle)
  qk_bf[h * 1024 + slot * 8 + (c & 7)] = f2bf(acc);
}

// ---------------- K1: flash-fused attention, phase-C on MFMA. grid 256 = 32 b x 8 parts, 512 thr ----------------
__global__ __launch_bounds__(512, 1) void k_fused3(const float* __restrict__ X,
                                                   const short* __restrict__ qk_bf,
                                                   const float* __restrict__ qb,
                                                   const int* __restrict__ idx,
                                                   const int* __restrict__ cnt,
                                                   short* __restrict__ Zt,
                                                   float* __restrict__ mt_g,
                                                   float* __restrict__ lt_g) {
  __shared__ short qlds[HEADS * 1024];   // 32 KB bf16, swizzle: slot = c8 ^ (h&7)
  __shared__ short xlds[TS * 1024];      // 64 KB bf16, swizzle: slot = c8 ^ (s&7) ^ ((s>>3)<<3)
  __shared__ short elbf[HEADS * 40];     // 1.25 KB: E[h][s] bf16, row stride 40 (pad)
  __shared__ short zst[HEADS * 1040];    // 32.5 KB: Z staging for coalesced out
  __shared__ float mt_l[32], lt_l[32], f_l[HEADS];
  __shared__ float mrun[2][HEADS], lrun[2][HEADS];
  int tid = threadIdx.x;
  int b = blockIdx.x >> 3, p = blockIdx.x & 7;
  int count = cnt[b];
  int chunk = (count + PARTS - 1) / PARTS;
  int pstart = p * chunk;
  int pend = pstart + chunk; if (pend > count) pend = count;
  int len = pend - pstart;
  int ntsub = (len + TS - 1) / TS;       // uniform per block
  {
    const short8v* qg = (const short8v*)qk_bf;
    short8v* ql = (short8v*)qlds;
    #pragma unroll
    for (int i = 0; i < 4; ++i) ql[tid + i * 512] = qg[tid + i * 512];
  }
  if (tid < HEADS) { mrun[0][tid] = -3e38f; lrun[0][tid] = 0.f; }
  int wv = tid >> 6, lane = tid & 63;
  int r16 = lane & 15, kg = lane >> 4;
  int hx = r16 & 7;
  const int* ib = idx + b * NN;
  const float* Xb = X + (size_t)b * NN * DIM;
  const short* qrow = qlds + r16 * 1024;
  float qbv = qb[r16];
  int srow = wv * 16 + r16;                       // QK^T A row (waves 0-1)
  int axor = (srow & 7) ^ (((srow >> 3) & 3) << 3);
  f32x4 acc[8];
  #pragma unroll
  for (int blk = 0; blk < 8; ++blk) acc[blk] = (f32x4){0.f, 0.f, 0.f, 0.f};
  float4 pfA[8], pfB[8];
  // initial prefetch (t=0)
  if (ntsub > 0) {
    #pragma unroll
    for (int k = 0; k < 8; ++k) {
      int i = tid + k * 512;
      int row = i >> 7, c8 = i & 127;
      int sl = pstart + row; if (sl >= pend) sl = pend - 1;
      int n = ib[sl];
      const float4* xg = (const float4*)(Xb + (size_t)n * DIM + c8 * 8);
      pfA[k] = xg[0]; pfB[k] = xg[1];
    }
  }
  __syncthreads();                       // qlds + mrun/lrun init visible

  for (int t = 0; t < ntsub; ++t) {
    int tb = pstart + t * TS;
    int tpar = t & 1;
    __syncthreads();                     // S0: prev tile's xlds/elbf/f_l readers done
    // ---- write prefetched X tile -> xlds ----
    #pragma unroll
    for (int k = 0; k < 8; ++k) {
      int i = tid + k * 512;
      int row = i >> 7, c8 = i & 127;
      int sw = c8 ^ (row & 7) ^ ((row >> 3) << 3);
      *(short8v*)(xlds + row * 1024 + sw * 8) = pack8(pfA[k], pfB[k]);
    }
    __syncthreads();                     // S1: xlds ready
    // ---- issue prefetch for t+1 ----
    if (t + 1 < ntsub) {
      int tb1 = pstart + (t + 1) * TS;
      #pragma unroll
      for (int k = 0; k < 8; ++k) {
        int i = tid + k * 512;
        int row = i >> 7, c8 = i & 127;
        int sl = tb1 + row; if (sl >= pend) sl = pend - 1;
        int n = ib[sl];
        const float4* xg = (const float4*)(Xb + (size_t)n * DIM + c8 * 8);
        pfA[k] = xg[0]; pfB[k] = xg[1];
      }
    }
    // ---- QK^T (waves 0-1): D[slot][head], col=head=r16 ----
    float s_[4]; int vld[4];
    if (wv < 2) {
      const short* arow = xlds + srow * 1024;
      f32x4 qa = {0.f, 0.f, 0.f, 0.f};
      #pragma unroll 8
      for (int m = 0; m < 32; ++m) {
        int c8 = 4 * m + kg;
        short8v af = *(const short8v*)(arow + ((c8 ^ axor) << 3));
        short8v bf = *(const short8v*)(qrow + ((c8 ^ hx) << 3));
        qa = __builtin_amdgcn_mfma_f32_16x16x32_bf16(af, bf, qa, 0, 0, 0);
      }
      float mw = -3e38f;
      #pragma unroll
      for (int j = 0; j < 4; ++j) {
        int slot = tb + wv * 16 + kg * 4 + j;
        vld[j] = slot < pend;
        s_[j] = vld[j] ? (qa[j] + qbv) * SCALE : -3e38f;
        mw = fmaxf(mw, s_[j]);
      }
      mw = fmaxf(mw, __shfl_xor(mw, 16));
      mw = fmaxf(mw, __shfl_xor(mw, 32));
      if (kg == 0) mt_l[wv * 16 + r16] = mw;
    }
    __syncthreads();                     // S2: mt_l ready
    if (wv < 2) {
      float m_t = fmaxf(mt_l[r16], mt_l[16 + r16]);
      float mo = mrun[tpar][r16];
      float mn = fmaxf(mo, m_t);
      float es = 0.f;
      #pragma unroll
      for (int j = 0; j < 4; ++j) {
        float e = vld[j] ? __expf(s_[j] - mn) : 0.f;
        elbf[r16 * 40 + (wv * 16 + kg * 4 + j)] = f2bf(e);
        es += e;
      }
      es += __shfl_xor(es, 16);
      es += __shfl_xor(es, 32);
      if (kg == 0) lt_l[wv * 16 + r16] = es;
      if (tid < 16) {
        f_l[tid] = __expf(mo - mn);
        mrun[tpar ^ 1][tid] = mn;
      }
    }
    __syncthreads();                     // S3: elbf, lt_l, f_l ready
    // ---- phase C (all 8 waves, MFMA): Z[h][c] += E[h][s] * X[s][c] over s=0..31 ----
    {
      int g = kg;                        // lane>>4
      float fj0 = f_l[g * 4 + 0], fj1 = f_l[g * 4 + 1];
      float fj2 = f_l[g * 4 + 2], fj3 = f_l[g * 4 + 3];
      #pragma unroll
      for (int blk = 0; blk < 8; ++blk) {
        acc[blk][0] *= fj0; acc[blk][1] *= fj1;
        acc[blk][2] *= fj2; acc[blk][3] *= fj3;
      }
      short8v ea = *(const short8v*)(elbf + r16 * 40 + g * 8);
      #pragma unroll
      for (int blk = 0; blk < 8; ++blk) {
        int c = wv * 128 + blk * 16 + r16;
        int ch = c >> 3, cl = c & 7;
        short8v xb;
        #pragma unroll
        for (int u = 0; u < 8; ++u) {
          int s = g * 8 + u;
          int sw = ch ^ (s & 7) ^ ((s >> 3) << 3);
          xb[u] = xlds[s * 1024 + sw * 8 + cl];
        }
        acc[blk] = __builtin_amdgcn_mfma_f32_16x16x32_bf16(ea, xb, acc[blk], 0, 0, 0);
      }
      if (tid < 16)
        lrun[tpar ^ 1][tid] = lrun[tpar][tid] * f_l[tid] + lt_l[tid] + lt_l[16 + tid];
    }
  }
  // ---- epilogue ----
  int par = ntsub & 1;
  if (tid < 16) {
    mt_g[(b * PARTS + p) * HEADS + tid] = mrun[par][tid];
    lt_g[(b * PARTS + p) * HEADS + tid] = lrun[par][tid];
  }
  // acc -> zst (D layout: row h = kg*4+j, col c = wv*128+blk*16+r16)
  #pragma unroll
  for (int blk = 0; blk < 8; ++blk) {
    int c = wv * 128 + blk * 16 + r16;
    #pragma unroll
    for (int j = 0; j < 4; ++j)
      zst[(kg * 4 + j) * 1040 + c] = f2bf(acc[blk][j]);
  }
  __syncthreads();
  short* zbase = Zt + ((size_t)(b * PARTS + p) * HEADS) * DIM;
  #pragma unroll
  for (int it = 0; it < 8; ++it) {
    int e4 = it * 2048 + tid * 4;
    int h = e4 >> 10, c = e4 & 1023;
    *(short4v*)(zbase + h * DIM + c) = *(const short4v*)(zst + h * 1040 + c);
  }
}

// ---------------- K2: reduce parts (flash rescale) + Wv projection ----------------
__global__ __launch_bounds__(256) void k_tov(const short* __restrict__ Zt,
                                             const float* __restrict__ mt_g,
                                             const float* __restrict__ lt_g,
                                             const float* __restrict__ Wv,
                                             float* __restrict__ T,
                                             float* __restrict__ lsum) {
  int b = blockIdx.x >> 4, h = blockIdx.x & 15;   // grid 512
  int tid = threadIdx.x;
  __shared__ float zlds[DIM];
  float m_b = -3e38f;
  #pragma unroll
  for (int t = 0; t < PARTS; ++t)
    m_b = fmaxf(m_b, mt_g[(b * PARTS + t) * HEADS + h]);
  float L = 0.f;
  #pragma unroll
  for (int t = 0; t < PARTS; ++t) {
    float lt = lt_g[(b * PARTS + t) * HEADS + h];
    if (lt > 0.f) L += lt * __expf(mt_g[(b * PARTS + t) * HEADS + h] - m_b);
  }
  float inv = L > 0.f ? 1.f / L : 0.f;
  float4 zs = make_float4(0.f, 0.f, 0.f, 0.f);
  #pragma unroll
  for (int t = 0; t < PARTS; ++t) {
    float lt = lt_g[(b * PARTS + t) * HEADS + h];
    if (lt <= 0.f) continue;
    float f = __expf(mt_g[(b * PARTS + t) * HEADS + h] - m_b) * inv;
    short4v z4 = *(const short4v*)(Zt + ((size_t)(b * PARTS + t) * HEADS + h) * DIM + tid * 4);
    zs.x += f * bf2f(z4[0]); zs.y += f * bf2f(z4[1]);
    zs.z += f * bf2f(z4[2]); zs.w += f * bf2f(z4[3]);
  }
  *(float4*)(zlds + tid * 4) = zs;
  __syncthreads();
  int wv = tid >> 6, lane = tid & 63;
  float4 zr[4];
  #pragma unroll
  for (int j = 0; j < 4; ++j) zr[j] = *(const float4*)(zlds + lane * 4 + j * 256);
  for (int i = 0; i < 16; ++i) {
    int df = h * 64 + wv * 16 + i;
    const float* wr = Wv + (size_t)df * DIM + lane * 4;
    float a = 0.f;
    #pragma unroll
    for (int j = 0; j < 4; ++j) {
      float4 w4 = *(const float4*)(wr + j * 256);
      a += zr[j].x * w4.x + zr[j].y * w4.y + zr[j].z * w4.z + zr[j].w * w4.w;
    }
    #pragma unroll
    for (int off = 32; off; off >>= 1) a += __shfl_xor(a, off);
    if (lane == 0) T[(size_t)b * DIM + df] = a;
  }
  if (tid == 0) lsum[b * HEADS + h] = L > 0.f ? 1.f : 0.f;
}

// ---------------- K3: U = LN0(S + T + l*bv) ----------------
__global__ void k_ln0(const float* __restrict__ S, const float* __restrict__ T,
                      const float* __restrict__ lsum, const float* __restrict__ bv,
                      const float* __restrict__ g0, const float* __restrict__ b0,
                      float* __restrict__ U) {
  __shared__ float red[4];
  int b = blockIdx.x, tid = threadIdx.x, d0 = tid * 4;   // grid 32
  float4 s4 = *(const float4*)(S + d0);
  float4 t4 = *(const float4*)(T + (size_t)b * DIM + d0);
  float4 v4 = *(const float4*)(bv + d0);
  float lh = lsum[b * HEADS + (d0 >> 6)];
  float x0 = s4.x + t4.x + lh * v4.x;
  float x1 = s4.y + t4.y + lh * v4.y;
  float x2 = s4.z + t4.z + lh * v4.z;
  float x3 = s4.w + t4.w + lh * v4.w;
  float mu = block_sum256(x0 + x1 + x2 + x3, red) * (1.f / DIM);
  float e0 = x0 - mu, e1 = x1 - mu, e2 = x2 - mu, e3 = x3 - mu;
  float var = block_sum256(e0 * e0 + e1 * e1 + e2 * e2 + e3 * e3, red) * (1.f / DIM);
  float r = rsqrtf(var + LN_EPS);
  float4 g4 = *(const float4*)(g0 + d0);
  float4 bb4 = *(const float4*)(b0 + d0);
  float4 o;
  o.x = e0 * r * g4.x + bb4.x;
  o.y = e1 * r * g4.y + bb4.y;
  o.z = e2 * r * g4.z + bb4.z;
  o.w = e3 * r * g4.w + bb4.w;
  *(float4*)(U + (size_t)b * DIM + d0) = o;
}

// ---------------- K4: R = relu(U . Wo^T + bo) ----------------
__global__ void k_wo(const float* __restrict__ U, const float* __restrict__ Wo,
                     const float* __restrict__ bo, float* __restrict__ R) {
  int wave = threadIdx.x >> 6, lane = threadIdx.x & 63;
  int dfb = blockIdx.x;                       // grid 256
  for (int dot = wave; dot < 128; dot += 4) {
    int b = dot >> 2, dfl = dot & 3;
    int df = dfb * 4 + dfl;
    const float* wr = Wo + (size_t)df * DIM + lane * 4;
    const float* ur = U + (size_t)b * DIM + lane * 4;
    float acc = 0.f;
    #pragma unroll
    for (int k = 0; k < 4; ++k) {
      float4 a = *(const float4*)(wr + k * 256);
      float4 u = *(const float4*)(ur + k * 256);
      acc += a.x * u.x + a.y * u.y + a.z * u.z + a.w * u.w;
    }
    #pragma unroll
    for (int off = 32; off; off >>= 1) acc += __shfl_xor(acc, off);
    if (lane == 0) R[(size_t)b * DIM + df] = fmaxf(acc + bo[df], 0.f);
  }
}

// ---------------- K5: out = LN1(U + R) ----------------
__global__ void k_ln1(const float* __restrict__ U, const float* __restrict__ R,
                      const float* __restrict__ g1, const float* __restrict__ b1,
                      float* __restrict__ out) {
  __shared__ float red[4];
  int b = blockIdx.x, tid = threadIdx.x, d0 = tid * 4;   // grid 32
  float4 u4 = *(const float4*)(U + (size_t)b * DIM + d0);
  float4 r4 = *(const float4*)(R + (size_t)b * DIM + d0);
  float x0 = u4.x + r4.x, x1 = u4.y + r4.y, x2 = u4.z + r4.z, x3 = u4.w + r4.w;
  float mu = block_sum256(x0 + x1 + x2 + x3, red) * (1.f / DIM);
  float e0 = x0 - mu, e1 = x1 - mu, e2 = x2 - mu, e3 = x3 - mu;
  float var = block_sum256(e0 * e0 + e1 * e1 + e2 * e2 + e3 * e3, red) * (1.f / DIM);
  float r = rsqrtf(var + LN_EPS);
  float4 g4 = *(const float4*)(g1 + d0);
  float4 bb4 = *(const float4*)(b1 + d0);
  float4 o;
  o.x = e0 * r * g4.x + bb4.x;
  o.y = e1 * r * g4.y + bb4.y;
  o.z = e2 * r * g4.z + bb4.z;
  o.w = e3 * r * g4.w + bb4.w;
  *(float4*)(out + (size_t)b * DIM + d0) = o;
}

extern "C" void kernel_launch(void* const* d_in, const int* in_sizes, int n_in,
                              void* d_out, int out_size, void* d_ws, size_t ws_size,
                              hipStream_t stream) {
  (void)in_sizes; (void)n_in; (void)out_size; (void)ws_size;
  const float* X  = (const float*)d_in[0];
  const int*   mask = (const int*)d_in[1];
  const float* S  = (const float*)d_in[2];
  const float* Wq = (const float*)d_in[3];
  const float* bq = (const float*)d_in[4];
  const float* Wk = (const float*)d_in[5];
  const float* bk = (const float*)d_in[6];
  const float* Wv = (const float*)d_in[7];
  const float* bv = (const float*)d_in[8];
  const float* Wo = (const float*)d_in[9];
  const float* bo = (const float*)d_in[10];
  const float* g0 = (const float*)d_in[11];
  const float* b0 = (const float*)d_in[12];
  const float* g1 = (const float*)d_in[13];
  const float* b1 = (const float*)d_in[14];
  float* out = (float*)d_out;

  char* base  = (char*)d_ws;
  size_t off = 0;
  short* Zt   = (short*)(base + off); off += (size_t)BB * PARTS * HEADS * DIM * 2;  // 8.4 MB
  short* qkbf = (short*)(base + off); off += HEADS * 1024 * 2;                      // 32 KB
  float* qb   = (float*)(base + off); off += 64;
  float* mt   = (float*)(base + off); off += (size_t)BB * PARTS * HEADS * 4;        // 16 KB
  float* lt   = (float*)(base + off); off += (size_t)BB * PARTS * HEADS * 4;        // 16 KB
  float* lsum = (float*)(base + off); off += BB * HEADS * 4;
  int*   idx  = (int*)(base + off);   off += (size_t)BB * NN * 4;                   // 256 KB
  int*   cnt  = (int*)(base + off);   off += 256;
  float* T    = (float*)(base + off); off += (size_t)BB * DIM * 4;
  float* U    = (float*)(base + off); off += (size_t)BB * DIM * 4;
  float* R    = (float*)(base + off); off += (size_t)BB * DIM * 4;

  k_front  <<<96,  256, 0, stream>>>(mask, S, Wq, bq, Wk, bk, qkbf, qb, idx, cnt);
  k_fused3 <<<256, 512, 0, stream>>>(X, qkbf, qb, idx, cnt, Zt, mt, lt);
  k_tov    <<<512, 256, 0, stream>>>(Zt, mt, lt, Wv, T, lsum);
  k_ln0    <<<32,  256, 0, stream>>>(S, T, lsum, bv, g0, b0, U);
  k_wo     <<<256, 256, 0, stream>>>(U, Wo, bo, R);
  k_ln1    <<<32,  256, 0, stream>>>(U, R, g1, b1, out);
}